// Round 2
// baseline (1797.486 us; speedup 1.0000x reference)
//
#include <hip/hip_runtime.h>
#include <stdint.h>

#define BATCH 512
#define TMAX  1024
#define DIN   4
#define H     64
#define NC    1098
#define RCH   32   // rec kernel: h0 rows staged in LDS per chunk (power of 2)

typedef __attribute__((ext_vector_type(2))) float v2;

__device__ __forceinline__ v2 mkv2(float a, float b) { v2 r; r.x = a; r.y = b; return r; }
__device__ __forceinline__ float sigmoidf_(float x) { return 1.0f / (1.0f + __expf(-x)); }
__device__ __forceinline__ float tanhf_(float x) { return 1.0f - 2.0f / (__expf(2.0f * x) + 1.0f); }
// bf16 helpers (RNE)
__device__ __forceinline__ uint32_t f2bf(float f) {
    uint32_t u = __float_as_uint(f);
    return (u + 0x7FFFu + ((u >> 16) & 1u)) >> 16;
}
__device__ __forceinline__ float bf2f(uint32_t h) { return __uint_as_float(h << 16); }

// ============ Layer 0: ONE WAVE per (seq, dir), ZERO per-step barriers ======
// Lane j owns gate rows {j, 64+j, 128+j, 192+j} = (i,f,g,o) of h-index j:
// the cell update is fully lane-local (no gate exchange, no barrier). h is
// broadcast via a wave-private LDS line; same-wave ds_write->ds_read is
// in-order (the pattern R0's hrep validated: no barrier between the write at
// step s and the cross-lane reads at s+1). 256 fp32 weight VGPRs/lane: legal
// at 1 wave/SIMD (512-reg budget with __launch_bounds__(128,1)); 512 blocks
// x 2 waves, 2 blocks/CU -> 4 waves on 4 SIMDs, one residency round.
__global__ __launch_bounds__(128, 1) void lstm_l0(
    const float* __restrict__ x, const int* __restrict__ lengths,
    const float* __restrict__ Wih_f, const float* __restrict__ Whh_f,
    const float* __restrict__ bih_f, const float* __restrict__ bhh_f,
    const float* __restrict__ Wih_b, const float* __restrict__ Whh_b,
    const float* __restrict__ bih_b, const float* __restrict__ bhh_b,
    uint16_t* __restrict__ h0b /* [B, T, 2H] bf16 */)
{
    const int b = blockIdx.x;
    const int t = threadIdx.x;
    const int j = t & 63, dir = t >> 6;   // wave 0 = fwd, wave 1 = bwd
    const int L = lengths[b];

    const float* Wih = dir ? Wih_b : Wih_f;
    const float* Whh = dir ? Whh_b : Whh_f;
    const float* bih = dir ? bih_b : bih_f;
    const float* bhh = dir ? bhh_b : bhh_f;

    v2 w[4][32];                          // 256 fp32 = 128 VGPR pairs
    #pragma unroll
    for (int g = 0; g < 4; g++) {
        const float4* pw = (const float4*)(Whh + (size_t)(64*g + j) * H);
        #pragma unroll
        for (int k = 0; k < 16; k++) {
            float4 a = pw[k];
            w[g][2*k]   = mkv2(a.x, a.y);
            w[g][2*k+1] = mkv2(a.z, a.w);
        }
    }
    float4 wx[4]; float bb[4];
    #pragma unroll
    for (int g = 0; g < 4; g++) {
        wx[g] = ((const float4*)Wih)[64*g + j];
        bb[g] = bih[64*g + j] + bhh[64*g + j];
    }

    __shared__ __align__(16) float4 xbuf[TMAX];   // 16 KB: whole x[b]
    __shared__ __align__(16) float  hbc[2][H];    // per-wave h broadcast line
    {
        const float4* x4 = (const float4*)x + (size_t)b * TMAX;
        for (int i = t; i < L; i += 128) xbuf[i] = x4[i];
    }
    hbc[dir][j] = 0.0f;
    float c = 0.0f;
    __syncthreads();                      // the ONLY barrier in this kernel

    uint16_t* outp = h0b + (size_t)b * TMAX * (2*H) + dir * H + j;

    for (int s = 0; s < L; s++) {
        const int tt = dir ? (L - 1 - s) : s;
        const float4 xt = xbuf[tt];       // uniform -> LDS broadcast
        float p[4];
        #pragma unroll
        for (int g = 0; g < 4; g++)
            p[g] = fmaf(wx[g].w, xt.w, fmaf(wx[g].z, xt.z,
                   fmaf(wx[g].y, xt.y, fmaf(wx[g].x, xt.x, bb[g]))));
        v2 a0[4], a1[4];
        #pragma unroll
        for (int g = 0; g < 4; g++) { a0[g] = mkv2(0.f,0.f); a1[g] = mkv2(0.f,0.f); }
        const float4* h4 = (const float4*)hbc[dir];
        #pragma unroll
        for (int k = 0; k < 16; k++) {
            float4 hv = h4[k];            // broadcast b128, conflict-free
            v2 lo = mkv2(hv.x, hv.y), hi = mkv2(hv.z, hv.w);
            #pragma unroll
            for (int g = 0; g < 4; g++) {
                a0[g] += w[g][2*k]   * lo;   // v_pk_fma_f32
                a1[g] += w[g][2*k+1] * hi;
            }
        }
        #pragma unroll
        for (int g = 0; g < 4; g++) { v2 sv = a0[g] + a1[g]; p[g] += sv.x + sv.y; }
        const float gi = sigmoidf_(p[0]);
        const float gf = sigmoidf_(p[1]);
        const float gg = tanhf_(p[2]);
        const float go = sigmoidf_(p[3]);
        c = fmaf(gf, c, gi * gg);
        const float h = go * tanhf_(c);
        hbc[dir][j] = h;                  // same-wave ordering, no barrier
        outp[(size_t)tt * (2*H)] = (uint16_t)f2bf(h);   // 128B/wave
    }
}

// ====== Layer 1: producer/consumer wave pipeline, ONE barrier per step ======
// (VERBATIM from the validated R0 kernel: 795 us, passed absmax 9.8e-4.)
// 512 threads, one sequence per block. Waves 0-3 (producers) compute the xW
// partials for step s+1 (wave w owns k-slice [32w,32w+32), lane j owns gates
// 4j..4j+3 -> 128 weight floats; 8 b128 broadcast reads + 1 b128 write).
// Waves 4-7 (consumers) own gate row (w-4)*64+j: gather 4 partials + bias,
// serial Whh dot on a private h replica, activation, parity exchange. Both
// phases overlap; parity double-buffering makes 1 barrier/step race-free.
__global__ __launch_bounds__(512) void lstm_rec_pipe(
    const uint16_t* __restrict__ h0b, const int* __restrict__ lengths,
    const float* __restrict__ Wih, const float* __restrict__ Whh,
    const float* __restrict__ bih, const float* __restrict__ bhh,
    const float* __restrict__ Wih_b,
    const float* __restrict__ bih_b, const float* __restrict__ bhh_b,
    const float* __restrict__ Wout, const float* __restrict__ bout,
    float* __restrict__ out)
{
    const int b = blockIdx.x;
    const int t = threadIdx.x;
    const int j = t & 63, w = t >> 6;   // w in 0..7
    const int L = lengths[b];
    const bool isProd = (w < 4);

    __shared__ __align__(16) float xch[RCH * 128];   // 16 KB: fp32 h0 rows
    __shared__ __align__(16) float part[2][4][256];  // 8 KB: xW partials
    __shared__ __align__(16) float hrep[4][H];       // consumer h replicas
    __shared__ __align__(16) float ex[2][4][H];      // parity gate exchange
    __shared__ __align__(16) float ybuf[2*H];

    v2 wreg[64];
    float bias = 0.0f;
    if (isProd) {
        #pragma unroll
        for (int q = 0; q < 4; q++) {
            const float4* pw = (const float4*)(Wih + (size_t)(4*j + q) * 128 + 32 * w);
            #pragma unroll
            for (int k = 0; k < 8; k++) {
                float4 v = pw[k];
                wreg[q*16 + 2*k]     = mkv2(v.x, v.y);
                wreg[q*16 + 2*k + 1] = mkv2(v.z, v.w);
            }
        }
    } else {
        const int g = (w - 4) * H + j;
        const float4* pw = (const float4*)(Whh + (size_t)g * H);
        #pragma unroll
        for (int k = 0; k < 16; k++) {
            float4 v = pw[k];
            wreg[2*k]     = mkv2(v.x, v.y);
            wreg[2*k + 1] = mkv2(v.z, v.w);
        }
        bias = bih[g] + bhh[g];
        hrep[w - 4][j] = 0.0f;   // own replica: same-wave ordering, no barrier
    }
    float c = 0.0f, h = 0.0f;

    auto produce = [&](int r, int p) {
        const float4* xr = (const float4*)(xch + r * 128 + 32 * w);
        v2 a0 = mkv2(0,0), a1 = mkv2(0,0), a2 = mkv2(0,0), a3 = mkv2(0,0);
        #pragma unroll
        for (int k = 0; k < 8; k++) {
            float4 xv = xr[k];                    // broadcast b128
            v2 xlo = mkv2(xv.x, xv.y), xhi = mkv2(xv.z, xv.w);
            a0 += wreg[ 0 + 2*k] * xlo; a0 += wreg[ 0 + 2*k + 1] * xhi;
            a1 += wreg[16 + 2*k] * xlo; a1 += wreg[16 + 2*k + 1] * xhi;
            a2 += wreg[32 + 2*k] * xlo; a2 += wreg[32 + 2*k + 1] * xhi;
            a3 += wreg[48 + 2*k] * xlo; a3 += wreg[48 + 2*k + 1] * xhi;
        }
        *(float4*)&part[p][w][4*j] =
            make_float4(a0.x + a0.y, a1.x + a1.y, a2.x + a2.y, a3.x + a3.y);
    };

    for (int s = 0; s < L; s++) {
        const int rr = s & (RCH - 1);
        if (rr == 0) {
            __syncthreads();                      // xch reuse safety
            const uint32_t* src = (const uint32_t*)(h0b + ((size_t)b * TMAX + s) * (2*H));
            for (int i = t; i < RCH * 64; i += 512) {
                uint32_t u = src[i];
                *(float2*)(xch + 2*i) = make_float2(bf2f(u & 0xFFFFu), bf2f(u >> 16));
            }
            __syncthreads();
            if (isProd) produce(0, s & 1);        // boundary row s
            __syncthreads();
        }
        if (isProd) {
            if (s + 1 < L && rr + 1 < RCH)        // lookahead: row s+1
                produce(rr + 1, (s + 1) & 1);
        } else {
            const int g = (w - 4) * H + j;
            const float pa = part[s & 1][0][g] + part[s & 1][1][g]
                           + part[s & 1][2][g] + part[s & 1][3][g];
            v2 a0 = mkv2(pa + bias, 0.0f), a1 = mkv2(0.0f, 0.0f);
            const float4* h4 = (const float4*)hrep[w - 4];
            #pragma unroll
            for (int k = 0; k < 16; k++) {
                float4 hv = h4[k];
                a0 += wreg[2*k]     * mkv2(hv.x, hv.y);
                a1 += wreg[2*k + 1] * mkv2(hv.z, hv.w);
            }
            const float a = (a0.x + a0.y) + (a1.x + a1.y);
            ex[s & 1][w - 4][j] = (w == 6) ? tanhf_(a) : sigmoidf_(a);
        }
        __syncthreads();                          // the per-step barrier
        if (!isProd) {
            const int p = s & 1;
            const float gi = ex[p][0][j], gf = ex[p][1][j];
            const float gg = ex[p][2][j], go = ex[p][3][j];
            c = fmaf(gf, c, gi * gg);
            h = go * tanhf_(c);
            hrep[w - 4][j] = h;
        }
    }

    // ---- epilogue: y = [h1f_last, h1b_first]; logits = y @ Wout^T + bout ---
    if (w == 4) ybuf[j] = h;                      // fwd last h
    __syncthreads();
    const float* xrow = xch + ((L - 1) & (RCH - 1)) * 128;  // h0 row L-1, fp32
    float* gb = &part[0][0][0];
    if (t < 256) {  // bwd first step, zero state -> Whh_l1b unused
        const float4* wb = (const float4*)(Wih_b + (size_t)t * 128);
        const float4* xv = (const float4*)xrow;
        v2 a0 = mkv2(bih_b[t] + bhh_b[t], 0.0f), a1 = mkv2(0.0f, 0.0f);
        #pragma unroll
        for (int k = 0; k < 32; k++) {
            float4 wv = wb[k], xk = xv[k];
            a0 += mkv2(wv.x, wv.y) * mkv2(xk.x, xk.y);
            a1 += mkv2(wv.z, wv.w) * mkv2(xk.z, xk.w);
        }
        const float a = (a0.x + a0.y) + (a1.x + a1.y);
        gb[t] = (t >= 128 && t < 192) ? tanhf_(a) : sigmoidf_(a);
    }
    __syncthreads();
    if (t < 64) {
        const float gi = gb[t], gg = gb[128 + t], go = gb[192 + t];
        ybuf[H + t] = go * tanhf_(gi * gg);       // c_prev = 0, f unused
    }
    __syncthreads();

    const float4* yv = (const float4*)ybuf;
    for (int o = t; o < NC; o += 512) {
        const float4* wr = (const float4*)(Wout + (size_t)o * (2*H));
        v2 a0 = mkv2(bout[o], 0.0f), a1 = mkv2(0.0f, 0.0f);
        #pragma unroll
        for (int k = 0; k < 32; k++) {
            float4 wv = wr[k], yy = yv[k];
            a0 += mkv2(wv.x, wv.y) * mkv2(yy.x, yy.y);
            a1 += mkv2(wv.z, wv.w) * mkv2(yy.z, yy.w);
        }
        out[(size_t)b * NC + o] = (a0.x + a0.y) + (a1.x + a1.y);
    }
}

extern "C" void kernel_launch(void* const* d_in, const int* in_sizes, int n_in,
                              void* d_out, int out_size, void* d_ws, size_t ws_size,
                              hipStream_t stream) {
    const float* x        = (const float*)d_in[0];
    const int*   lengths  = (const int*)  d_in[1];
    const float* Wih_l0f  = (const float*)d_in[2];
    const float* Whh_l0f  = (const float*)d_in[3];
    const float* bih_l0f  = (const float*)d_in[4];
    const float* bhh_l0f  = (const float*)d_in[5];
    const float* Wih_l0b  = (const float*)d_in[6];
    const float* Whh_l0b  = (const float*)d_in[7];
    const float* bih_l0b  = (const float*)d_in[8];
    const float* bhh_l0b  = (const float*)d_in[9];
    const float* Wih_l1f  = (const float*)d_in[10];
    const float* Whh_l1f  = (const float*)d_in[11];
    const float* bih_l1f  = (const float*)d_in[12];
    const float* bhh_l1f  = (const float*)d_in[13];
    const float* Wih_l1b  = (const float*)d_in[14];
    // d_in[15] = Whh_l1b: unused (backward dir only needs its first step, h=0)
    const float* bih_l1b  = (const float*)d_in[16];
    const float* bhh_l1b  = (const float*)d_in[17];
    const float* Wout     = (const float*)d_in[18];
    const float* bout     = (const float*)d_in[19];
    float* out = (float*)d_out;

    // ws: h0 bf16 [B, T, 2H] = 128 MiB
    uint16_t* h0b = (uint16_t*)d_ws;

    lstm_l0<<<dim3(BATCH), 128, 0, stream>>>(
        x, lengths,
        Wih_l0f, Whh_l0f, bih_l0f, bhh_l0f,
        Wih_l0b, Whh_l0b, bih_l0b, bhh_l0b, h0b);

    lstm_rec_pipe<<<dim3(BATCH), 512, 0, stream>>>(
        h0b, lengths,
        Wih_l1f, Whh_l1f, bih_l1f, bhh_l1f,
        Wih_l1b, bih_l1b, bhh_l1b, Wout, bout, out);
}

// Round 3
// 1340.082 us; speedup vs baseline: 1.3413x; 1.3413x over previous
//
#include <hip/hip_runtime.h>
#include <stdint.h>

#define BATCH 512
#define TMAX  1024
#define DIN   4
#define H     64
#define NC    1098
#define RCH   32   // rec kernel: h0 rows staged in LDS per chunk (power of 2)

typedef __attribute__((ext_vector_type(2))) float    v2;
typedef __attribute__((ext_vector_type(2))) _Float16 h2;

__device__ __forceinline__ v2 mkv2(float a, float b) { v2 r; r.x = a; r.y = b; return r; }
__device__ __forceinline__ float sigmoidf_(float x) { return 1.0f / (1.0f + __expf(-x)); }
__device__ __forceinline__ float tanhf_(float x) { return 1.0f - 2.0f / (__expf(2.0f * x) + 1.0f); }
// bf16 helpers (RNE)
__device__ __forceinline__ uint32_t f2bf(float f) {
    uint32_t u = __float_as_uint(f);
    return (u + 0x7FFFu + ((u >> 16) & 1u)) >> 16;
}
__device__ __forceinline__ float bf2f(uint32_t h) { return __uint_as_float(h << 16); }
__device__ __forceinline__ h2 u2h(uint32_t u) { union { uint32_t u; h2 h; } c; c.u = u; return c.h; }

__device__ __forceinline__ float fdot2_(h2 w, h2 x, float acc) {
    // v_dot2_f32_f16: fp32 acc += w.x*x.x + w.y*x.y (2 MACs/op, f16 inputs)
    return __builtin_amdgcn_fdot2(w, x, acc, false);
}

// ============ Layer 0: ONE WAVE per (seq, dir), ZERO per-step barriers ======
// R2 validated this structure's CORRECTNESS (lane-local 4 gates, same-wave
// LDS h-broadcast with no barrier) but the fp32 weight array (256 floats +
// working set) exceeded the v0-v255 architectural budget -> wholesale spill
// (VGPR_Count=176, ~2450cyc/step scratch reloads). Fix: Whh in PACKED FP16
// (128 VGPRs), MACs via v_dot2_f32_f16 (same 2-MAC/op issue rate as
// v_pk_fma_f32), h broadcast as f16. ~180 VGPRs total, BARE
// __launch_bounds__(128) (the (N,minwaves) form provably triggers array
// spill on this kernel family). c and all accumulation stay fp32.
__global__ __launch_bounds__(128) void lstm_l0(
    const float* __restrict__ x, const int* __restrict__ lengths,
    const float* __restrict__ Wih_f, const float* __restrict__ Whh_f,
    const float* __restrict__ bih_f, const float* __restrict__ bhh_f,
    const float* __restrict__ Wih_b, const float* __restrict__ Whh_b,
    const float* __restrict__ bih_b, const float* __restrict__ bhh_b,
    uint16_t* __restrict__ h0b /* [B, T, 2H] bf16 */)
{
    const int b = blockIdx.x;
    const int t = threadIdx.x;
    const int j = t & 63, dir = t >> 6;   // wave 0 = fwd, wave 1 = bwd
    const int L = lengths[b];

    const float* Wih = dir ? Wih_b : Wih_f;
    const float* Whh = dir ? Whh_b : Whh_f;
    const float* bih = dir ? bih_b : bih_f;
    const float* bhh = dir ? bhh_b : bhh_f;

    h2 wh[4][32];                         // 256 f16 = 128 VGPRs
    #pragma unroll
    for (int g = 0; g < 4; g++) {
        const float4* pw = (const float4*)(Whh + (size_t)(64*g + j) * H);
        #pragma unroll
        for (int k = 0; k < 16; k++) {
            float4 a = pw[k];
            h2 lo; lo.x = (_Float16)a.x; lo.y = (_Float16)a.y;
            h2 hi; hi.x = (_Float16)a.z; hi.y = (_Float16)a.w;
            wh[g][2*k]   = lo;
            wh[g][2*k+1] = hi;
        }
    }
    float4 wx[4]; float bb[4];
    #pragma unroll
    for (int g = 0; g < 4; g++) {
        wx[g] = ((const float4*)Wih)[64*g + j];
        bb[g] = bih[64*g + j] + bhh[64*g + j];
    }

    __shared__ __align__(16) float4    xbuf[TMAX];    // 16 KB: whole x[b]
    __shared__ __align__(16) _Float16  hb16[2][H];    // per-wave h line (f16)
    {
        const float4* x4 = (const float4*)x + (size_t)b * TMAX;
        for (int i = t; i < L; i += 128) xbuf[i] = x4[i];
    }
    hb16[dir][j] = (_Float16)0.0f;
    float c = 0.0f;
    __syncthreads();                      // the ONLY barrier in this kernel

    uint16_t* outp = h0b + (size_t)b * TMAX * (2*H) + dir * H + j;

    for (int s = 0; s < L; s++) {
        const int tt = dir ? (L - 1 - s) : s;
        const float4 xt = xbuf[tt];       // uniform -> LDS broadcast
        float p[4];
        #pragma unroll
        for (int g = 0; g < 4; g++)
            p[g] = fmaf(wx[g].w, xt.w, fmaf(wx[g].z, xt.z,
                   fmaf(wx[g].y, xt.y, fmaf(wx[g].x, xt.x, bb[g]))));
        float acA[4] = {0.f,0.f,0.f,0.f}, acB[4] = {0.f,0.f,0.f,0.f};
        const uint4* h4 = (const uint4*)&hb16[dir][0];
        #pragma unroll
        for (int q = 0; q < 8; q++) {
            uint4 u = h4[q];              // broadcast b128: 8 f16 of h
            h2 p0 = u2h(u.x), p1 = u2h(u.y), p2 = u2h(u.z), p3 = u2h(u.w);
            #pragma unroll
            for (int g = 0; g < 4; g++) { // 2 accum chains/gate (16-deep)
                acA[g] = fdot2_(wh[g][4*q+0], p0, acA[g]);
                acA[g] = fdot2_(wh[g][4*q+1], p1, acA[g]);
                acB[g] = fdot2_(wh[g][4*q+2], p2, acB[g]);
                acB[g] = fdot2_(wh[g][4*q+3], p3, acB[g]);
            }
        }
        #pragma unroll
        for (int g = 0; g < 4; g++) p[g] += acA[g] + acB[g];
        const float gi = sigmoidf_(p[0]);
        const float gf = sigmoidf_(p[1]);
        const float gg = tanhf_(p[2]);
        const float go = sigmoidf_(p[3]);
        c = fmaf(gf, c, gi * gg);
        const float h = go * tanhf_(c);
        hb16[dir][j] = (_Float16)h;       // same-wave ordering, no barrier
        outp[(size_t)tt * (2*H)] = (uint16_t)f2bf(h);   // 128B/wave
    }
}

// ====== Layer 1: producer/consumer wave pipeline, ONE barrier per step ======
// (VERBATIM from the validated R0 kernel: 795 us, passed absmax 9.8e-4.)
__global__ __launch_bounds__(512) void lstm_rec_pipe(
    const uint16_t* __restrict__ h0b, const int* __restrict__ lengths,
    const float* __restrict__ Wih, const float* __restrict__ Whh,
    const float* __restrict__ bih, const float* __restrict__ bhh,
    const float* __restrict__ Wih_b,
    const float* __restrict__ bih_b, const float* __restrict__ bhh_b,
    const float* __restrict__ Wout, const float* __restrict__ bout,
    float* __restrict__ out)
{
    const int b = blockIdx.x;
    const int t = threadIdx.x;
    const int j = t & 63, w = t >> 6;   // w in 0..7
    const int L = lengths[b];
    const bool isProd = (w < 4);

    __shared__ __align__(16) float xch[RCH * 128];   // 16 KB: fp32 h0 rows
    __shared__ __align__(16) float part[2][4][256];  // 8 KB: xW partials
    __shared__ __align__(16) float hrep[4][H];       // consumer h replicas
    __shared__ __align__(16) float ex[2][4][H];      // parity gate exchange
    __shared__ __align__(16) float ybuf[2*H];

    v2 wreg[64];
    float bias = 0.0f;
    if (isProd) {
        #pragma unroll
        for (int q = 0; q < 4; q++) {
            const float4* pw = (const float4*)(Wih + (size_t)(4*j + q) * 128 + 32 * w);
            #pragma unroll
            for (int k = 0; k < 8; k++) {
                float4 v = pw[k];
                wreg[q*16 + 2*k]     = mkv2(v.x, v.y);
                wreg[q*16 + 2*k + 1] = mkv2(v.z, v.w);
            }
        }
    } else {
        const int g = (w - 4) * H + j;
        const float4* pw = (const float4*)(Whh + (size_t)g * H);
        #pragma unroll
        for (int k = 0; k < 16; k++) {
            float4 v = pw[k];
            wreg[2*k]     = mkv2(v.x, v.y);
            wreg[2*k + 1] = mkv2(v.z, v.w);
        }
        bias = bih[g] + bhh[g];
        hrep[w - 4][j] = 0.0f;   // own replica: same-wave ordering, no barrier
    }
    float c = 0.0f, h = 0.0f;

    auto produce = [&](int r, int p) {
        const float4* xr = (const float4*)(xch + r * 128 + 32 * w);
        v2 a0 = mkv2(0,0), a1 = mkv2(0,0), a2 = mkv2(0,0), a3 = mkv2(0,0);
        #pragma unroll
        for (int k = 0; k < 8; k++) {
            float4 xv = xr[k];                    // broadcast b128
            v2 xlo = mkv2(xv.x, xv.y), xhi = mkv2(xv.z, xv.w);
            a0 += wreg[ 0 + 2*k] * xlo; a0 += wreg[ 0 + 2*k + 1] * xhi;
            a1 += wreg[16 + 2*k] * xlo; a1 += wreg[16 + 2*k + 1] * xhi;
            a2 += wreg[32 + 2*k] * xlo; a2 += wreg[32 + 2*k + 1] * xhi;
            a3 += wreg[48 + 2*k] * xlo; a3 += wreg[48 + 2*k + 1] * xhi;
        }
        *(float4*)&part[p][w][4*j] =
            make_float4(a0.x + a0.y, a1.x + a1.y, a2.x + a2.y, a3.x + a3.y);
    };

    for (int s = 0; s < L; s++) {
        const int rr = s & (RCH - 1);
        if (rr == 0) {
            __syncthreads();                      // xch reuse safety
            const uint32_t* src = (const uint32_t*)(h0b + ((size_t)b * TMAX + s) * (2*H));
            for (int i = t; i < RCH * 64; i += 512) {
                uint32_t u = src[i];
                *(float2*)(xch + 2*i) = make_float2(bf2f(u & 0xFFFFu), bf2f(u >> 16));
            }
            __syncthreads();
            if (isProd) produce(0, s & 1);        // boundary row s
            __syncthreads();
        }
        if (isProd) {
            if (s + 1 < L && rr + 1 < RCH)        // lookahead: row s+1
                produce(rr + 1, (s + 1) & 1);
        } else {
            const int g = (w - 4) * H + j;
            const float pa = part[s & 1][0][g] + part[s & 1][1][g]
                           + part[s & 1][2][g] + part[s & 1][3][g];
            v2 a0 = mkv2(pa + bias, 0.0f), a1 = mkv2(0.0f, 0.0f);
            const float4* h4 = (const float4*)hrep[w - 4];
            #pragma unroll
            for (int k = 0; k < 16; k++) {
                float4 hv = h4[k];
                a0 += wreg[2*k]     * mkv2(hv.x, hv.y);
                a1 += wreg[2*k + 1] * mkv2(hv.z, hv.w);
            }
            const float a = (a0.x + a0.y) + (a1.x + a1.y);
            ex[s & 1][w - 4][j] = (w == 6) ? tanhf_(a) : sigmoidf_(a);
        }
        __syncthreads();                          // the per-step barrier
        if (!isProd) {
            const int p = s & 1;
            const float gi = ex[p][0][j], gf = ex[p][1][j];
            const float gg = ex[p][2][j], go = ex[p][3][j];
            c = fmaf(gf, c, gi * gg);
            h = go * tanhf_(c);
            hrep[w - 4][j] = h;
        }
    }

    // ---- epilogue: y = [h1f_last, h1b_first]; logits = y @ Wout^T + bout ---
    if (w == 4) ybuf[j] = h;                      // fwd last h
    __syncthreads();
    const float* xrow = xch + ((L - 1) & (RCH - 1)) * 128;  // h0 row L-1, fp32
    float* gb = &part[0][0][0];
    if (t < 256) {  // bwd first step, zero state -> Whh_l1b unused
        const float4* wb = (const float4*)(Wih_b + (size_t)t * 128);
        const float4* xv = (const float4*)xrow;
        v2 a0 = mkv2(bih_b[t] + bhh_b[t], 0.0f), a1 = mkv2(0.0f, 0.0f);
        #pragma unroll
        for (int k = 0; k < 32; k++) {
            float4 wv = wb[k], xk = xv[k];
            a0 += mkv2(wv.x, wv.y) * mkv2(xk.x, xk.y);
            a1 += mkv2(wv.z, wv.w) * mkv2(xk.z, xk.w);
        }
        const float a = (a0.x + a0.y) + (a1.x + a1.y);
        gb[t] = (t >= 128 && t < 192) ? tanhf_(a) : sigmoidf_(a);
    }
    __syncthreads();
    if (t < 64) {
        const float gi = gb[t], gg = gb[128 + t], go = gb[192 + t];
        ybuf[H + t] = go * tanhf_(gi * gg);       // c_prev = 0, f unused
    }
    __syncthreads();

    const float4* yv = (const float4*)ybuf;
    for (int o = t; o < NC; o += 512) {
        const float4* wr = (const float4*)(Wout + (size_t)o * (2*H));
        v2 a0 = mkv2(bout[o], 0.0f), a1 = mkv2(0.0f, 0.0f);
        #pragma unroll
        for (int k = 0; k < 32; k++) {
            float4 wv = wr[k], yy = yv[k];
            a0 += mkv2(wv.x, wv.y) * mkv2(yy.x, yy.y);
            a1 += mkv2(wv.z, wv.w) * mkv2(yy.z, yy.w);
        }
        out[(size_t)b * NC + o] = (a0.x + a0.y) + (a1.x + a1.y);
    }
}

extern "C" void kernel_launch(void* const* d_in, const int* in_sizes, int n_in,
                              void* d_out, int out_size, void* d_ws, size_t ws_size,
                              hipStream_t stream) {
    const float* x        = (const float*)d_in[0];
    const int*   lengths  = (const int*)  d_in[1];
    const float* Wih_l0f  = (const float*)d_in[2];
    const float* Whh_l0f  = (const float*)d_in[3];
    const float* bih_l0f  = (const float*)d_in[4];
    const float* bhh_l0f  = (const float*)d_in[5];
    const float* Wih_l0b  = (const float*)d_in[6];
    const float* Whh_l0b  = (const float*)d_in[7];
    const float* bih_l0b  = (const float*)d_in[8];
    const float* bhh_l0b  = (const float*)d_in[9];
    const float* Wih_l1f  = (const float*)d_in[10];
    const float* Whh_l1f  = (const float*)d_in[11];
    const float* bih_l1f  = (const float*)d_in[12];
    const float* bhh_l1f  = (const float*)d_in[13];
    const float* Wih_l1b  = (const float*)d_in[14];
    // d_in[15] = Whh_l1b: unused (backward dir only needs its first step, h=0)
    const float* bih_l1b  = (const float*)d_in[16];
    const float* bhh_l1b  = (const float*)d_in[17];
    const float* Wout     = (const float*)d_in[18];
    const float* bout     = (const float*)d_in[19];
    float* out = (float*)d_out;

    // ws: h0 bf16 [B, T, 2H] = 128 MiB
    uint16_t* h0b = (uint16_t*)d_ws;

    lstm_l0<<<dim3(BATCH), 128, 0, stream>>>(
        x, lengths,
        Wih_l0f, Whh_l0f, bih_l0f, bhh_l0f,
        Wih_l0b, Whh_l0b, bih_l0b, bhh_l0b, h0b);

    lstm_rec_pipe<<<dim3(BATCH), 512, 0, stream>>>(
        h0b, lengths,
        Wih_l1f, Whh_l1f, bih_l1f, bhh_l1f,
        Wih_l1b, bih_l1b, bhh_l1b, Wout, bout, out);
}

// Round 6
// 1211.634 us; speedup vs baseline: 1.4835x; 1.1060x over previous
//
#include <hip/hip_runtime.h>
#include <stdint.h>

#define BATCH 512
#define TMAX  1024
#define NC    1098
#define H     64
#define CH    8    // layer-1 xW chunk: one block-barrier per CH steps

typedef __attribute__((ext_vector_type(2))) float    v2;
typedef __attribute__((ext_vector_type(2))) _Float16 h2;

__device__ __forceinline__ v2 mkv2(float a, float b) { v2 r; r.x = a; r.y = b; return r; }
__device__ __forceinline__ float sigmoidf_(float x) { return 1.0f / (1.0f + __expf(-x)); }
__device__ __forceinline__ float tanhf_(float x) { return 1.0f - 2.0f / (__expf(2.0f * x) + 1.0f); }
__device__ __forceinline__ h2 u2h(uint32_t u) { union { uint32_t u; h2 h; } c; c.u = u; return c.h; }

__device__ __forceinline__ float fdot2_(h2 w, h2 x, float acc) {
    // v_dot2_f32_f16: fp32 acc += w.x*x.x + w.y*x.y (validated in R3)
    return __builtin_amdgcn_fdot2(w, x, acc, false);
}

// ============ Layer 0: paired sequences, 4 waves/block, zero step barriers ==
// R3 validated the one-wave f16-dot2 inner loop (this is a verbatim copy).
// Block bk owns seqs {bk, 511-bk} (lengths sorted descending => paired
// total work ~constant); 4 waves = 2 seqs x 2 dirs; 256 blocks.
__global__ __launch_bounds__(256) void lstm_l0(
    const float* __restrict__ x, const int* __restrict__ lengths,
    const float* __restrict__ Wih_f, const float* __restrict__ Whh_f,
    const float* __restrict__ bih_f, const float* __restrict__ bhh_f,
    const float* __restrict__ Wih_b, const float* __restrict__ Whh_b,
    const float* __restrict__ bih_b, const float* __restrict__ bhh_b,
    _Float16* __restrict__ h0 /* [B, T, 128] f16 */)
{
    const int bk = blockIdx.x;
    const int t = threadIdx.x;
    const int j = t & 63, w = t >> 6;     // w in 0..3
    const int seq = (w < 2) ? bk : (BATCH - 1 - bk);
    const int dir = w & 1;
    const int xb  = w >> 1;               // which xbuf
    const int L = lengths[seq];

    const float* Wih = dir ? Wih_b : Wih_f;
    const float* Whh = dir ? Whh_b : Whh_f;
    const float* bih = dir ? bih_b : bih_f;
    const float* bhh = dir ? bhh_b : bhh_f;

    h2 wh[4][32];                         // 256 f16 = 128 VGPRs
    #pragma unroll
    for (int g = 0; g < 4; g++) {
        const float4* pw = (const float4*)(Whh + (size_t)(64*g + j) * H);
        #pragma unroll
        for (int k = 0; k < 16; k++) {
            float4 a = pw[k];
            h2 lo; lo.x = (_Float16)a.x; lo.y = (_Float16)a.y;
            h2 hi; hi.x = (_Float16)a.z; hi.y = (_Float16)a.w;
            wh[g][2*k]   = lo;
            wh[g][2*k+1] = hi;
        }
    }
    float4 wx[4]; float bb[4];
    #pragma unroll
    for (int g = 0; g < 4; g++) {
        wx[g] = ((const float4*)Wih)[64*g + j];
        bb[g] = bih[64*g + j] + bhh[64*g + j];
    }

    __shared__ __align__(16) float4    xbuf[2][TMAX];  // 32 KB: x of both seqs
    __shared__ __align__(16) _Float16  hln[4][H];      // per-wave h line (f16)
    {
        const int sA = bk, sB = BATCH - 1 - bk;
        const int LA = lengths[sA], LB = lengths[sB];
        const float4* xA = (const float4*)x + (size_t)sA * TMAX;
        const float4* xB = (const float4*)x + (size_t)sB * TMAX;
        for (int i = t; i < LA; i += 256) xbuf[0][i] = xA[i];
        for (int i = t; i < LB; i += 256) xbuf[1][i] = xB[i];
    }
    hln[w][j] = (_Float16)0.0f;
    float c = 0.0f;
    __syncthreads();                      // the ONLY barrier in this kernel

    _Float16* outp = h0 + (size_t)seq * TMAX * 128 + dir * H + j;

    for (int s = 0; s < L; s++) {
        const int tt = dir ? (L - 1 - s) : s;
        const float4 xt = xbuf[xb][tt];   // uniform -> LDS broadcast
        float p[4];
        #pragma unroll
        for (int g = 0; g < 4; g++)
            p[g] = fmaf(wx[g].w, xt.w, fmaf(wx[g].z, xt.z,
                   fmaf(wx[g].y, xt.y, fmaf(wx[g].x, xt.x, bb[g]))));
        float acA[4] = {0.f,0.f,0.f,0.f}, acB[4] = {0.f,0.f,0.f,0.f};
        const uint4* h4 = (const uint4*)&hln[w][0];
        #pragma unroll
        for (int q = 0; q < 8; q++) {
            uint4 u = h4[q];              // broadcast b128: 8 f16 of h
            h2 p0 = u2h(u.x), p1 = u2h(u.y), p2 = u2h(u.z), p3 = u2h(u.w);
            #pragma unroll
            for (int g = 0; g < 4; g++) { // 2 accum chains/gate
                acA[g] = fdot2_(wh[g][4*q+0], p0, acA[g]);
                acA[g] = fdot2_(wh[g][4*q+1], p1, acA[g]);
                acB[g] = fdot2_(wh[g][4*q+2], p2, acB[g]);
                acB[g] = fdot2_(wh[g][4*q+3], p3, acB[g]);
            }
        }
        #pragma unroll
        for (int g = 0; g < 4; g++) p[g] += acA[g] + acB[g];
        const float gi = sigmoidf_(p[0]);
        const float gf = sigmoidf_(p[1]);
        const float gg = tanhf_(p[2]);
        const float go = sigmoidf_(p[3]);
        c = fmaf(gf, c, gi * gg);
        const float h = go * tanhf_(c);
        hln[w][j] = (_Float16)h;          // same-wave ordering, no barrier
        outp[(size_t)tt * 128] = (_Float16)h;
    }
}

// ====== Layer 1: 1 consumer + 2 producer waves per seq, barrier per CH=8 ====
// Structure unchanged from R5. R5's failure (absmax 3.6e-2) was the epilogue
// DOUBLE-ACTIVATION bug: gb already stores activated gates (sigma(i), tanh(g),
// sigma(o)) but the combine re-applied sigma/tanh. Fixed to the R0-validated
// combine: hb = sigma(o) * tanh(sigma(i) * tanh(g)) using gb values directly.
__global__ __launch_bounds__(384) void lstm_l1(
    const _Float16* __restrict__ h0, const int* __restrict__ lengths,
    const float* __restrict__ Wih,  const float* __restrict__ Whh,
    const float* __restrict__ bih,  const float* __restrict__ bhh,
    const float* __restrict__ WihB, const float* __restrict__ bihB,
    const float* __restrict__ bhhB,
    const float* __restrict__ Wout, const float* __restrict__ bout,
    float* __restrict__ out)
{
    const int bk = blockIdx.x;
    const int t = threadIdx.x;
    const int grp = (t >= 192) ? 1 : 0;
    const int tl = t - 192 * grp;         // 0..191 within group
    const int wl = tl >> 6;               // 0 consumer, 1..2 producers
    const int l = tl & 63;
    const int seq = grp ? (BATCH - 1 - bk) : bk;
    const int L = lengths[seq];
    const int nch = (L + CH - 1) / CH;
    const int nchMax = (lengths[bk] + CH - 1) / CH;  // L[bk] >= L[511-bk]

    __shared__ __align__(16) float    xw[2][2][CH][256];   // 32 KB xW dbuf
    __shared__ __align__(16) _Float16 hst[2][2][CH][128];  // 8 KB h0 dbuf
    __shared__ __align__(16) _Float16 hln[2][H];           // consumer h lines
    __shared__ __align__(16) float    ybuf[2][2*H];
    __shared__ __align__(16) float    gb[2][192];
    __shared__ __align__(16) float    h0r[2][128];

    const _Float16* hseq = h0 + (size_t)seq * TMAX * 128;

    // wsh is UNION'd: consumer = Whh rows {g*64+l} (4x32 h2);
    // producer = Wih rows {rA, rB} (2x64 h2). Keeps footprint at 128 regs.
    h2 wsh[128];
    float bb[4] = {0.f, 0.f, 0.f, 0.f};
    int rA = 0, rB = 0;
    if (wl == 0) {
        #pragma unroll
        for (int g = 0; g < 4; g++) {
            const float4* pw = (const float4*)(Whh + (size_t)(64*g + l) * H);
            #pragma unroll
            for (int k = 0; k < 16; k++) {
                float4 a = pw[k];
                h2 lo; lo.x = (_Float16)a.x; lo.y = (_Float16)a.y;
                h2 hi; hi.x = (_Float16)a.z; hi.y = (_Float16)a.w;
                wsh[g*32 + 2*k]   = lo;
                wsh[g*32 + 2*k+1] = hi;
            }
            bb[g] = bih[64*g + l] + bhh[64*g + l];
        }
        hln[grp][l] = (_Float16)0.0f;     // own-wave line, no barrier needed
    } else {
        const int pw = wl - 1;
        rA = pw * 128 + l; rB = pw * 128 + 64 + l;
        const float4* pa = (const float4*)(Wih + (size_t)rA * 128);
        const float4* pb = (const float4*)(Wih + (size_t)rB * 128);
        #pragma unroll
        for (int k = 0; k < 32; k++) {
            float4 a = pa[k], b2 = pb[k];
            h2 alo; alo.x = (_Float16)a.x;  alo.y = (_Float16)a.y;
            h2 ahi; ahi.x = (_Float16)a.z;  ahi.y = (_Float16)a.w;
            h2 blo; blo.x = (_Float16)b2.x; blo.y = (_Float16)b2.y;
            h2 bhi; bhi.x = (_Float16)b2.z; bhi.y = (_Float16)b2.w;
            wsh[2*k]        = alo;
            wsh[2*k + 1]    = ahi;
            wsh[64 + 2*k]   = blo;
            wsh[64 + 2*k+1] = bhi;
        }
    }

    uint4 st0;                            // producer staging reg (16B/lane)
    auto stage_load = [&](int ck) {       // chunk = CH*128 f16 = 2KB = 128 uint4
        const uint4* gp = (const uint4*)(hseq + (size_t)ck * CH * 128);
        st0 = gp[(wl - 1) * 64 + l];      // 2 waves x 64 lanes cover it
    };
    auto stage_store = [&](int ck) {
        uint4* dp = (uint4*)&hst[grp][ck & 1][0][0];
        dp[(wl - 1) * 64 + l] = st0;
    };
    auto produce = [&](int ck) {
        const int par = ck & 1;
        for (int r = 0; r < CH; r++) {
            const uint4* rp = (const uint4*)&hst[grp][par][r][0];
            float aA = 0.f, aB = 0.f;
            #pragma unroll
            for (int q = 0; q < 16; q++) {
                uint4 u = rp[q];          // broadcast b128: 8 f16 of h0 row
                h2 p0 = u2h(u.x), p1 = u2h(u.y), p2 = u2h(u.z), p3 = u2h(u.w);
                aA = fdot2_(wsh[4*q+0], p0, aA);
                aA = fdot2_(wsh[4*q+1], p1, aA);
                aA = fdot2_(wsh[4*q+2], p2, aA);
                aA = fdot2_(wsh[4*q+3], p3, aA);
                aB = fdot2_(wsh[64+4*q+0], p0, aB);
                aB = fdot2_(wsh[64+4*q+1], p1, aB);
                aB = fdot2_(wsh[64+4*q+2], p2, aB);
                aB = fdot2_(wsh[64+4*q+3], p3, aB);
            }
            xw[grp][par][r][rA] = aA;     // stride-1 across lanes
            xw[grp][par][r][rB] = aB;
        }
    };

    float c = 0.f, h = 0.f;

    // prologue: hst0 staged -> barrier -> produce(0), hst1 staged -> barrier
    if (wl >= 1) { stage_load(0); stage_store(0); if (nch > 1) stage_load(1); }
    __syncthreads();
    if (wl >= 1) { produce(0); if (nch > 1) stage_store(1); }
    __syncthreads();

    for (int cc = 0; cc < nchMax; cc++) {
        if (wl == 0) {
            const int sbeg = cc * CH;
            const int send = (sbeg + CH < L) ? (sbeg + CH) : L;
            const int par = cc & 1;
            for (int s = sbeg; s < send; s++) {
                const int r = s - sbeg;
                float p[4];
                #pragma unroll
                for (int g = 0; g < 4; g++)
                    p[g] = xw[grp][par][r][g*64 + l] + bb[g];
                float acA[4] = {0.f,0.f,0.f,0.f}, acB[4] = {0.f,0.f,0.f,0.f};
                const uint4* h4 = (const uint4*)&hln[grp][0];
                #pragma unroll
                for (int q = 0; q < 8; q++) {
                    uint4 u = h4[q];
                    h2 p0 = u2h(u.x), p1 = u2h(u.y), p2 = u2h(u.z), p3 = u2h(u.w);
                    #pragma unroll
                    for (int g = 0; g < 4; g++) {
                        acA[g] = fdot2_(wsh[g*32+4*q+0], p0, acA[g]);
                        acA[g] = fdot2_(wsh[g*32+4*q+1], p1, acA[g]);
                        acB[g] = fdot2_(wsh[g*32+4*q+2], p2, acB[g]);
                        acB[g] = fdot2_(wsh[g*32+4*q+3], p3, acB[g]);
                    }
                }
                #pragma unroll
                for (int g = 0; g < 4; g++) p[g] += acA[g] + acB[g];
                const float gi = sigmoidf_(p[0]);
                const float gf = sigmoidf_(p[1]);
                const float gg = tanhf_(p[2]);
                const float go = sigmoidf_(p[3]);
                c = fmaf(gf, c, gi * gg);
                h = go * tanhf_(c);
                hln[grp][l] = (_Float16)h;    // own-wave, no barrier
            }
        } else {
            if (cc + 2 < nch) stage_load(cc + 2);   // issue early (T14)
            if (cc + 1 < nch) produce(cc + 1);      // fill xw[(cc+1)&1]
            if (cc + 2 < nch) stage_store(cc + 2);  // hst[cc&1]: free, read done
        }
        __syncthreads();                  // ONE barrier per CH steps
    }

    // ---- epilogue: y = [h1f_last, h1b_first]; logits = y @ Wout^T + bout ---
    if (wl == 0) ybuf[grp][l] = h;        // fwd last h
    if (tl < 128) h0r[grp][tl] = (float)hseq[(size_t)(L - 1) * 128 + tl];
    __syncthreads();
    {
        // bwd first step (c_prev=0): rows i(0-63), g(128-191), o(192-255)
        const int row = (tl < 64) ? tl : (tl + 64);
        const float4* wr = (const float4*)(WihB + (size_t)row * 128);
        const float4* xr = (const float4*)&h0r[grp][0];
        v2 a0 = mkv2(bihB[row] + bhhB[row], 0.f), a1 = mkv2(0.f, 0.f);
        #pragma unroll
        for (int k = 0; k < 32; k++) {
            float4 wv = wr[k], xv = xr[k];
            a0 += mkv2(wv.x, wv.y) * mkv2(xv.x, xv.y);
            a1 += mkv2(wv.z, wv.w) * mkv2(xv.z, xv.w);
        }
        const float a = (a0.x + a0.y) + (a1.x + a1.y);
        gb[grp][tl] = (tl >= 64 && tl < 128) ? tanhf_(a) : sigmoidf_(a);
    }
    __syncthreads();
    if (tl < 64) {
        // gb holds ACTIVATED gates: gb[tl]=sigma(i), gb[64+tl]=tanh(g),
        // gb[128+tl]=sigma(o). Combine raw (R5 bug: re-applied sigma/tanh here).
        const float hb = gb[grp][128 + tl] * tanhf_(gb[grp][tl] * gb[grp][64 + tl]);
        ybuf[grp][H + tl] = hb;
    }
    __syncthreads();
    const float4* yv = (const float4*)&ybuf[grp][0];
    for (int o = tl; o < NC; o += 192) {
        const float4* wr = (const float4*)(Wout + (size_t)o * 128);
        v2 a0 = mkv2(bout[o], 0.f), a1 = mkv2(0.f, 0.f);
        #pragma unroll
        for (int k = 0; k < 32; k++) {
            float4 wv = wr[k], yy = yv[k];
            a0 += mkv2(wv.x, wv.y) * mkv2(yy.x, yy.y);
            a1 += mkv2(wv.z, wv.w) * mkv2(yy.z, yy.w);
        }
        out[(size_t)seq * NC + o] = (a0.x + a0.y) + (a1.x + a1.y);
    }
}

extern "C" void kernel_launch(void* const* d_in, const int* in_sizes, int n_in,
                              void* d_out, int out_size, void* d_ws, size_t ws_size,
                              hipStream_t stream) {
    const float* x        = (const float*)d_in[0];
    const int*   lengths  = (const int*)  d_in[1];
    const float* Wih_l0f  = (const float*)d_in[2];
    const float* Whh_l0f  = (const float*)d_in[3];
    const float* bih_l0f  = (const float*)d_in[4];
    const float* bhh_l0f  = (const float*)d_in[5];
    const float* Wih_l0b  = (const float*)d_in[6];
    const float* Whh_l0b  = (const float*)d_in[7];
    const float* bih_l0b  = (const float*)d_in[8];
    const float* bhh_l0b  = (const float*)d_in[9];
    const float* Wih_l1f  = (const float*)d_in[10];
    const float* Whh_l1f  = (const float*)d_in[11];
    const float* bih_l1f  = (const float*)d_in[12];
    const float* bhh_l1f  = (const float*)d_in[13];
    const float* Wih_l1b  = (const float*)d_in[14];
    // d_in[15] = Whh_l1b: unused (backward dir only needs its first step, h=0)
    const float* bih_l1b  = (const float*)d_in[16];
    const float* bhh_l1b  = (const float*)d_in[17];
    const float* Wout     = (const float*)d_in[18];
    const float* bout     = (const float*)d_in[19];
    float* out = (float*)d_out;

    // ws: h0 f16 [B, T, 128] = 128 MiB
    _Float16* h0 = (_Float16*)d_ws;

    lstm_l0<<<dim3(BATCH / 2), 256, 0, stream>>>(
        x, lengths,
        Wih_l0f, Whh_l0f, bih_l0f, bhh_l0f,
        Wih_l0b, Whh_l0b, bih_l0b, bhh_l0b, h0);

    lstm_l1<<<dim3(BATCH / 2), 384, 0, stream>>>(
        h0, lengths,
        Wih_l1f, Whh_l1f, bih_l1f, bhh_l1f,
        Wih_l1b, bih_l1b, bhh_l1b, Wout, bout, out);
}